// Round 1
// baseline (177.486 us; speedup 1.0000x reference)
//
#include <hip/hip_runtime.h>

#define NB 4
#define CCH 256
#define NN 4096
#define DD 32

typedef __attribute__((ext_vector_type(8))) short bf16x8;
typedef __attribute__((ext_vector_type(8))) _Float16 f16x8;
typedef __attribute__((ext_vector_type(2))) __fp16 fp16x2;
typedef __attribute__((ext_vector_type(4))) float f32x4;

#define MFB(a,b,c) __builtin_amdgcn_mfma_f32_16x16x32_bf16(a,b,c,0,0,0)
#define MFH(a,b,c) __builtin_amdgcn_mfma_f32_16x16x32_f16(a,b,c,0,0,0)
#define L2E 1.44269504f

__device__ inline unsigned short f2bf(float f){
    union { float f; unsigned u; } v; v.f = f;
    unsigned r = v.u + 0x7fffu + ((v.u >> 16) & 1u);
    return (unsigned short)(r >> 16);
}
__device__ inline float bfval(unsigned short h){
    union { unsigned u; float f; } v; v.u = ((unsigned)h) << 16; return v.f;
}
// native transcendental: D = 2^S0 (exactly what SL-folded softmax needs)
__device__ inline float vexp2(float x){
    float r; asm("v_exp_f32 %0, %1" : "=v"(r) : "v"(x)); return r;
}
__device__ inline double pkpair(float p0, float p1, float p2, float p3){
    union { fp16x2 h2[2]; double d; } u;
    u.h2[0] = __builtin_amdgcn_cvt_pkrtz(p0, p1);
    u.h2[1] = __builtin_amdgcn_cvt_pkrtz(p2, p3);
    return u.d;
}

// ---------------------------------------------------------------- proj_qk
__global__ __launch_bounds__(256) void proj_qk(
    const float* __restrict__ x,
    const float* __restrict__ wq, const float* __restrict__ bq,
    const float* __restrict__ wk, const float* __restrict__ bk,
    unsigned short* __restrict__ q_hi, unsigned short* __restrict__ q_lo,
    unsigned short* __restrict__ k_hi, unsigned short* __restrict__ k_lo)
{
    const int t = threadIdx.x;
    const int w = t >> 6;
    const int l = t & 63;
    const int lr = l & 15, lg = l >> 4;
    const int nb = blockIdx.x;
    const int b  = blockIdx.y;
    const int n0 = nb*64 + w*16;
    const int n  = n0 + lr;

    const float* xb = x + (size_t)b*CCH*NN;

    f32x4 acc[4] = {};

    for (int kc = 0; kc < 8; kc++) {
        const int cbase = kc*32 + lg*8;
        float xv[8];
        #pragma unroll
        for (int e = 0; e < 8; e++)
            xv[e] = xb[(size_t)(cbase + e)*NN + n];
        bf16x8 xh, xl;
        #pragma unroll
        for (int e = 0; e < 8; e++) {
            unsigned short h = f2bf(xv[e]);
            xh[e] = (short)h;
            xl[e] = (short)f2bf(xv[e] - bfval(h));
        }
        #pragma unroll
        for (int f = 0; f < 4; f++) {
            const float* wrow = (f < 2) ? (wq + (size_t)(f*16 + lr)*CCH)
                                        : (wk + (size_t)((f-2)*16 + lr)*CCH);
            float4 a4 = *(const float4*)(wrow + cbase);
            float4 b4 = *(const float4*)(wrow + cbase + 4);
            float wv8[8] = {a4.x,a4.y,a4.z,a4.w,b4.x,b4.y,b4.z,b4.w};
            bf16x8 wh, wl;
            #pragma unroll
            for (int e = 0; e < 8; e++) {
                unsigned short h = f2bf(wv8[e]);
                wh[e] = (short)h;
                wl[e] = (short)f2bf(wv8[e] - bfval(h));
            }
            acc[f] = MFB(xh, wl, acc[f]);
            acc[f] = MFB(xl, wh, acc[f]);
            acc[f] = MFB(xh, wh, acc[f]);
        }
    }

    #pragma unroll
    for (int f = 0; f < 4; f++) {
        const int d = (f & 1)*16 + lr;
        const bool isq = (f < 2);
        float bias = isq ? bq[d] : bk[d];
        unsigned short* hi = isq ? q_hi : k_hi;
        unsigned short* lo = isq ? q_lo : k_lo;
        #pragma unroll
        for (int r = 0; r < 4; r++) {
            int nn = n0 + lg*4 + r;
            float val = acc[f][r] + bias;
            unsigned short h = f2bf(val);
            unsigned short l2 = f2bf(val - bfval(h));
            size_t a = ((size_t)(b*NN + nn))*DD + d;
            hi[a] = h;
            lo[a] = l2;
        }
    }
}

// ---------------------------------------------------------------- proj_v
// Output layout BLOCKED: v16[b][ib=n/8][c][8] (f16), 16B per (ib,c) chunk.
__global__ __launch_bounds__(512) void proj_v(
    const float* __restrict__ x,
    const float* __restrict__ wv, const float* __restrict__ bv,
    _Float16* __restrict__ v16)
{
    const int t = threadIdx.x;
    const int w = t >> 6;
    const int cg = w >> 2;
    const int ng = w & 3;
    const int l = t & 63;
    const int lr = l & 15, lg = l >> 4;
    const int ob = blockIdx.x;
    const int nb = blockIdx.y;
    const int b  = blockIdx.z;
    const int n0 = nb*64 + ng*16;
    const int n  = n0 + lr;
    const int cbase0 = ob*128 + cg*64;

    const float* xb = x + (size_t)b*CCH*NN;

    f32x4 acc[4] = {};

    for (int kc = 0; kc < 8; kc++) {
        const int kbase = kc*32 + lg*8;
        float xv[8];
        #pragma unroll
        for (int e = 0; e < 8; e++)
            xv[e] = xb[(size_t)(kbase + e)*NN + n];
        bf16x8 xh, xl;
        #pragma unroll
        for (int e = 0; e < 8; e++) {
            unsigned short h = f2bf(xv[e]);
            xh[e] = (short)h;
            xl[e] = (short)f2bf(xv[e] - bfval(h));
        }
        #pragma unroll
        for (int f = 0; f < 4; f++) {
            const float* wrow = wv + (size_t)(cbase0 + f*16 + lr)*CCH;
            float4 a4 = *(const float4*)(wrow + kbase);
            float4 b4 = *(const float4*)(wrow + kbase + 4);
            float wv8[8] = {a4.x,a4.y,a4.z,a4.w,b4.x,b4.y,b4.z,b4.w};
            bf16x8 wh, wl;
            #pragma unroll
            for (int e = 0; e < 8; e++) {
                unsigned short h = f2bf(wv8[e]);
                wh[e] = (short)h;
                wl[e] = (short)f2bf(wv8[e] - bfval(h));
            }
            acc[f] = MFB(wl, xh, acc[f]);
            acc[f] = MFB(wh, xl, acc[f]);
            acc[f] = MFB(wh, xh, acc[f]);
        }
    }

    const size_t bslice = (size_t)b*(NN/8);
    #pragma unroll
    for (int f = 0; f < 4; f++) {
        #pragma unroll
        for (int r = 0; r < 4; r++) {
            int c = cbase0 + f*16 + lg*4 + r;
            float val = acc[f][r] + bv[c];
            v16[(((bslice + (n >> 3))*CCH + c) << 3) + (n & 7)] = (_Float16)val;
        }
    }
}

// ---------------------------------------------------------------- stats
// No max-tracking (energies bounded; 2^65 and sums << f32 max).
// Z = sum_j 2^(e*L2E) over a j-half; native v_exp_f32; K pointer-walk.
__global__ __launch_bounds__(512) void stats_kernel(
    const unsigned short* __restrict__ qh, const unsigned short* __restrict__ ql,
    const unsigned short* __restrict__ kh, const unsigned short* __restrict__ kl,
    float* __restrict__ Zp)
{
    __shared__ float zW[8][64];
    const int t = threadIdx.x;
    const int w = t >> 6;
    const int l = t & 63;
    const int lr = l & 15, lg = l >> 4;
    const int it = blockIdx.x;   // 0..63 : i-tile
    const int jc = blockIdx.y;   // 0..1  : j-half (2048 j each)
    const int b  = blockIdx.z;
    const int ibase = it*64;
    const f32x4 zero = {0.f,0.f,0.f,0.f};

    bf16x8 qfh[4], qfl[4];
    #pragma unroll
    for (int f = 0; f < 4; f++) {
        size_t a = ((size_t)(b*NN + ibase + f*16 + lr))*DD + lg*8;
        qfh[f] = *(const bf16x8*)(qh + a);
        qfl[f] = *(const bf16x8*)(ql + a);
    }
    float Z[4] = {0.f, 0.f, 0.f, 0.f};

    const size_t k0 = ((size_t)(b*NN + jc*2048 + w*16 + lr))*DD + lg*8;
    const unsigned short* kp  = kh + k0;
    const unsigned short* klp = kl + k0;

    for (int jt = 0; jt < 16; ++jt) {
        bf16x8 kfh2 = *(const bf16x8*)kp;
        bf16x8 kfl2 = *(const bf16x8*)klp;
        #pragma unroll
        for (int f = 0; f < 4; f++) {
            f32x4 e = MFB(kfl2, qfh[f], zero);
            e = MFB(kfh2, qfl[f], e);
            e = MFB(kfh2, qfh[f], e);
            Z[f] += vexp2(e[0]*L2E) + vexp2(e[1]*L2E)
                  + vexp2(e[2]*L2E) + vexp2(e[3]*L2E);
        }
        kp  += 128*DD;
        klp += 128*DD;
    }
    #pragma unroll
    for (int f = 0; f < 4; f++) {
        Z[f] += __shfl_xor(Z[f], 16, 64);
        Z[f] += __shfl_xor(Z[f], 32, 64);
        if (lg == 0) zW[w][f*16 + lr] = Z[f];
    }
    __syncthreads();
    if (t < 64) {
        float z = 0.f;
        #pragma unroll
        for (int w2 = 0; w2 < 8; ++w2) z += zW[w2][t];
        Zp[((size_t)jc*NB + b)*NN + ibase + t] = z;
    }
}

// ---------------------------------------------------------------- combine
__global__ __launch_bounds__(256) void combine_kernel(
    const float* __restrict__ Zp, float* __restrict__ Sx)
{
    const int idx = blockIdx.x*256 + threadIdx.x;   // b*NN + i, 16384 total
    Sx[idx] = log2f(Zp[idx] + Zp[(size_t)NB*NN + idx]);
}

// ---------------------------------------------------------------- attn
// R14: c-tile split 128->64, grid 512->1024, LDS 48KB->32KB per block
// -> 4 resident blocks/CU (was 2). Occupancy was the binding constraint
// (MfmaUtil 22%, VALUBusy 22%, HBM 2%, Occ 19%). QK/exp recomputed per
// ct-slice (x4 instead of x2) -- cheap vs doubling latency-hiding.
// Same one-barrier/iter dbuf pipeline, same swizzles.
__global__ __launch_bounds__(256, 4) void attn_kernel(
    const unsigned short* __restrict__ qh, const unsigned short* __restrict__ ql,
    const unsigned short* __restrict__ kh, const unsigned short* __restrict__ kl,
    const _Float16* __restrict__ v16,
    const float* __restrict__ Sx,
    const float* __restrict__ x, const float* __restrict__ gamma,
    float* __restrict__ out)
{
    __shared__ __align__(16) char Pb[2][8192];    // P [64j][64i] f16 swz, dbuf
    __shared__ __align__(16) char Wb[2][8192];    // W [64c][64i] f16 swz, dbuf

    const int t = threadIdx.x;
    const int w = t >> 6;
    const int jw = w >> 1;       // 0..1
    const int cw = w & 1;        // 0..1
    const int l = t & 63;
    const int lr = l & 15, lg = l >> 4;

    // XCD slice: blocks with equal lin&15 share one (b, ct).
    // lin%8 picks the XCD -> each XCD holds 2 slices (~2.1MB, L2-resident).
    const int lin = blockIdx.x;
    const int slice = lin & 15;
    const int b   = slice >> 2;
    const int ct  = slice & 3;
    const int jt  = lin >> 4;    // 0..63
    const int jbase = jt*64, cbase = ct*64;

    // K B-fragments for jfr {2jw, 2jw+1} (fixed all kernel)
    bf16x8 kfh[2], kfl[2];
    #pragma unroll
    for (int jj = 0; jj < 2; jj++) {
        size_t a = ((size_t)(b*NN + jbase + (2*jw+jj)*16 + lr))*DD + lg*8;
        kfh[jj] = *(const bf16x8*)(kh + a);
        kfl[jj] = *(const bf16x8*)(kl + a);
    }

    const float* Sb = Sx + (size_t)b*NN;
    const _Float16* vb = v16 + (size_t)b*(NN/8)*CCH*8;

    // W staging: thread t covers c-row sc = t&63, q-chunks sq0..sq0+1
    const int sc  = t & 63;
    const int sq0 = (t >> 6) * 2;

    // ---------------- prologue: W(0), P(0) ----------------
    #pragma unroll
    for (int k = 0; k < 2; k++) {
        const int q = sq0 + k;
        f16x8 v = *(const f16x8*)(vb + (((size_t)q*CCH + cbase + sc) << 3));
        *(f16x8*)(Wb[0] + sc*128 + ((q ^ (sc & 7))*16)) = v;
    }
    {
        #pragma unroll
        for (int ii = 0; ii < 2; ii++) {
            const int ifr = 2*cw + ii;
            size_t a = ((size_t)(b*NN + ifr*16 + lr))*DD + lg*8;
            bf16x8 qh2 = *(const bf16x8*)(qh + a);
            bf16x8 ql2 = *(const bf16x8*)(ql + a);
            float4 s4 = *(const float4*)(Sb + ifr*16 + lg*4);
            #pragma unroll
            for (int jj = 0; jj < 2; jj++) {
                f32x4 e = {};
                e = MFB(ql2, kfh[jj], e);
                e = MFB(qh2, kfl[jj], e);
                e = MFB(qh2, kfh[jj], e);
                double pk = pkpair(
                    vexp2(fmaf(e[0], L2E, -s4.x)),
                    vexp2(fmaf(e[1], L2E, -s4.y)),
                    vexp2(fmaf(e[2], L2E, -s4.z)),
                    vexp2(fmaf(e[3], L2E, -s4.w)));
                const int j = (2*jw+jj)*16 + lr;
                const int slot = (ifr*2 + (lg>>1)) ^ (lr & 7);
                *(double*)(Pb[0] + j*128 + slot*16 + (lg&1)*8) = pk;
            }
        }
    }
    __syncthreads();

    // walking pointers at it+1 = 1 positions
    const _Float16* wp = vb + (((size_t)(8 + sq0)*CCH + cbase + sc) << 3);
    const unsigned short* qhp =
        qh + ((size_t)(b*NN + 64 + 2*cw*16 + lr))*DD + lg*8;
    const unsigned short* qlp =
        ql + ((size_t)(b*NN + 64 + 2*cw*16 + lr))*DD + lg*8;
    const float* sp = Sb + 64 + 2*cw*16 + lg*4;

    char* Pcur = Pb[0]; char* Pnxt = Pb[1];
    char* Wcur = Wb[0]; char* Wnxt = Wb[1];

    f32x4 acc[2][2] = {};   // [jj][cf]

    for (int it = 0; it < 64; ++it) {
        const bool more = (it < 63);

        // ---- 1. issue global loads for it+1 (pointer walks) ----
        f16x8 ws[2];
        bf16x8 qfh2[2], qfl2[2];
        float4 s4[2];
        if (more) {
            #pragma unroll
            for (int k = 0; k < 2; k++)
                ws[k] = *(const f16x8*)(wp + k*(CCH*8));
            #pragma unroll
            for (int ii = 0; ii < 2; ii++) {
                qfh2[ii] = *(const bf16x8*)(qhp + ii*16*DD);
                qfl2[ii] = *(const bf16x8*)(qlp + ii*16*DD);
                s4[ii]   = *(const float4*)(sp + ii*16);
            }
        }

        // ---- 2. PV(it) from Pcur, Wcur ----
        f16x8 pa[2][2];
        #pragma unroll
        for (int jj = 0; jj < 2; jj++) {
            const int j = (2*jw+jj)*16 + lr;
            #pragma unroll
            for (int ic = 0; ic < 2; ic++) {
                const int slot = (ic*4 + lg) ^ (lr & 7);
                pa[jj][ic] = *(const f16x8*)(Pcur + j*128 + slot*16);
            }
        }
        __builtin_amdgcn_s_setprio(1);
        #pragma unroll
        for (int ic = 0; ic < 2; ic++) {
            #pragma unroll
            for (int cf = 0; cf < 2; cf++) {
                const int crow = (2*cw+cf)*16 + lr;
                const int slot = (ic*4 + lg) ^ (crow & 7);
                f16x8 wf = *(const f16x8*)(Wcur + crow*128 + slot*16);
                acc[0][cf] = MFH(pa[0][ic], wf, acc[0][cf]);
                acc[1][cf] = MFH(pa[1][ic], wf, acc[1][cf]);
            }
        }
        __builtin_amdgcn_s_setprio(0);

        // ---- 3. QK(it+1) + exp/pack ; 4. write Pnxt, Wnxt ----
        if (more) {
            #pragma unroll
            for (int ii = 0; ii < 2; ii++) {
                const int ifr = 2*cw + ii;
                #pragma unroll
                for (int jj = 0; jj < 2; jj++) {
                    f32x4 e = {};
                    e = MFB(qfl2[ii], kfh[jj], e);
                    e = MFB(qfh2[ii], kfl[jj], e);
                    e = MFB(qfh2[ii], kfh[jj], e);
                    double pk = pkpair(
                        vexp2(fmaf(e[0], L2E, -s4[ii].x)),
                        vexp2(fmaf(e[1], L2E, -s4[ii].y)),
                        vexp2(fmaf(e[2], L2E, -s4[ii].z)),
                        vexp2(fmaf(e[3], L2E, -s4[ii].w)));
                    const int j = (2*jw+jj)*16 + lr;
                    const int slot = (ifr*2 + (lg>>1)) ^ (lr & 7);
                    *(double*)(Pnxt + j*128 + slot*16 + (lg&1)*8) = pk;
                }
            }
            #pragma unroll
            for (int k = 0; k < 2; k++) {
                const int q = sq0 + k;
                *(f16x8*)(Wnxt + sc*128 + ((q ^ (sc & 7))*16)) = ws[k];
            }
        }
        __syncthreads();

        wp  += 8*CCH*8;     // next i-tile (8 ib-steps)
        qhp += 64*DD;
        qlp += 64*DD;
        sp  += 64;
        char* tp = Pcur; Pcur = Pnxt; Pnxt = tp;
        char* tw = Wcur; Wcur = Wnxt; Wnxt = tw;
    }

    // epilogue: direct float4 stores (j in regs, 4 consecutive n)
    const float gam = gamma[0];
    #pragma unroll
    for (int jj = 0; jj < 2; jj++) {
        #pragma unroll
        for (int cf = 0; cf < 2; cf++) {
            const int c = cbase + (2*cw+cf)*16 + lr;
            const int j = jbase + (2*jw+jj)*16 + lg*4;
            size_t o = ((size_t)(b*CCH + c))*NN + j;
            float4 xv = *(const float4*)(x + o);
            float4 ov;
            ov.x = fmaf(gam, acc[jj][cf][0], xv.x);
            ov.y = fmaf(gam, acc[jj][cf][1], xv.y);
            ov.z = fmaf(gam, acc[jj][cf][2], xv.z);
            ov.w = fmaf(gam, acc[jj][cf][3], xv.w);
            *(float4*)(out + o) = ov;
        }
    }
}

// ---------------------------------------------------------------- launch
extern "C" void kernel_launch(void* const* d_in, const int* in_sizes, int n_in,
                              void* d_out, int out_size, void* d_ws, size_t ws_size,
                              hipStream_t stream)
{
    (void)in_sizes; (void)n_in; (void)out_size; (void)ws_size;
    const float* x     = (const float*)d_in[0];
    const float* wq    = (const float*)d_in[1];
    const float* bq    = (const float*)d_in[2];
    const float* wk    = (const float*)d_in[3];
    const float* bk    = (const float*)d_in[4];
    const float* wv    = (const float*)d_in[5];
    const float* bv    = (const float*)d_in[6];
    const float* gamma = (const float*)d_in[7];
    float* out = (float*)d_out;

    char* ws = (char*)d_ws;
    unsigned short* q_hi = (unsigned short*)(ws + 0x000000);  // 1MB
    unsigned short* q_lo = (unsigned short*)(ws + 0x100000);  // 1MB
    unsigned short* k_hi = (unsigned short*)(ws + 0x200000);  // 1MB
    unsigned short* k_lo = (unsigned short*)(ws + 0x300000);  // 1MB
    _Float16*       v16  = (_Float16*)      (ws + 0x400000);  // 8MB blocked
    float*          Zp   = (float*)         (ws + 0xC00000);  // 128KB partials
    float*          Sx   = (float*)         (ws + 0xC20000);  // 64KB (SL)

    proj_qk<<<dim3(64, 4),    256, 0, stream>>>(x, wq, bq, wk, bk,
                                                q_hi, q_lo, k_hi, k_lo);
    proj_v <<<dim3(2, 64, 4), 512, 0, stream>>>(x, wv, bv, v16);
    stats_kernel  <<<dim3(64, 2, 4), 512, 0, stream>>>(q_hi, q_lo, k_hi, k_lo, Zp);
    combine_kernel<<<dim3(64),       256, 0, stream>>>(Zp, Sx);
    attn_kernel   <<<dim3(1024),     256, 0, stream>>>(
        q_hi, q_lo, k_hi, k_lo, v16, Sx, x, gamma, out);
}

// Round 2
// 172.971 us; speedup vs baseline: 1.0261x; 1.0261x over previous
//
#include <hip/hip_runtime.h>

#define NB 4
#define CCH 256
#define NN 4096
#define DD 32

typedef __attribute__((ext_vector_type(8))) short bf16x8;
typedef __attribute__((ext_vector_type(8))) _Float16 f16x8;
typedef __attribute__((ext_vector_type(2))) __fp16 fp16x2;
typedef __attribute__((ext_vector_type(4))) float f32x4;

#define MFB(a,b,c) __builtin_amdgcn_mfma_f32_16x16x32_bf16(a,b,c,0,0,0)
#define MFH(a,b,c) __builtin_amdgcn_mfma_f32_16x16x32_f16(a,b,c,0,0,0)
#define L2E 1.44269504f

__device__ inline unsigned short f2bf(float f){
    union { float f; unsigned u; } v; v.f = f;
    unsigned r = v.u + 0x7fffu + ((v.u >> 16) & 1u);
    return (unsigned short)(r >> 16);
}
__device__ inline float bfval(unsigned short h){
    union { unsigned u; float f; } v; v.u = ((unsigned)h) << 16; return v.f;
}
// native transcendental: D = 2^S0 (exactly what SL-folded softmax needs)
__device__ inline float vexp2(float x){
    float r; asm("v_exp_f32 %0, %1" : "=v"(r) : "v"(x)); return r;
}
__device__ inline double pkpair(float p0, float p1, float p2, float p3){
    union { fp16x2 h2[2]; double d; } u;
    u.h2[0] = __builtin_amdgcn_cvt_pkrtz(p0, p1);
    u.h2[1] = __builtin_amdgcn_cvt_pkrtz(p2, p3);
    return u.d;
}

// ---------------------------------------------------------------- proj_qk
__global__ __launch_bounds__(256) void proj_qk(
    const float* __restrict__ x,
    const float* __restrict__ wq, const float* __restrict__ bq,
    const float* __restrict__ wk, const float* __restrict__ bk,
    unsigned short* __restrict__ q_hi, unsigned short* __restrict__ q_lo,
    unsigned short* __restrict__ k_hi, unsigned short* __restrict__ k_lo)
{
    const int t = threadIdx.x;
    const int w = t >> 6;
    const int l = t & 63;
    const int lr = l & 15, lg = l >> 4;
    const int nb = blockIdx.x;
    const int b  = blockIdx.y;
    const int n0 = nb*64 + w*16;
    const int n  = n0 + lr;

    const float* xb = x + (size_t)b*CCH*NN;

    f32x4 acc[4] = {};

    for (int kc = 0; kc < 8; kc++) {
        const int cbase = kc*32 + lg*8;
        float xv[8];
        #pragma unroll
        for (int e = 0; e < 8; e++)
            xv[e] = xb[(size_t)(cbase + e)*NN + n];
        bf16x8 xh, xl;
        #pragma unroll
        for (int e = 0; e < 8; e++) {
            unsigned short h = f2bf(xv[e]);
            xh[e] = (short)h;
            xl[e] = (short)f2bf(xv[e] - bfval(h));
        }
        #pragma unroll
        for (int f = 0; f < 4; f++) {
            const float* wrow = (f < 2) ? (wq + (size_t)(f*16 + lr)*CCH)
                                        : (wk + (size_t)((f-2)*16 + lr)*CCH);
            float4 a4 = *(const float4*)(wrow + cbase);
            float4 b4 = *(const float4*)(wrow + cbase + 4);
            float wv8[8] = {a4.x,a4.y,a4.z,a4.w,b4.x,b4.y,b4.z,b4.w};
            bf16x8 wh, wl;
            #pragma unroll
            for (int e = 0; e < 8; e++) {
                unsigned short h = f2bf(wv8[e]);
                wh[e] = (short)h;
                wl[e] = (short)f2bf(wv8[e] - bfval(h));
            }
            acc[f] = MFB(xh, wl, acc[f]);
            acc[f] = MFB(xl, wh, acc[f]);
            acc[f] = MFB(xh, wh, acc[f]);
        }
    }

    #pragma unroll
    for (int f = 0; f < 4; f++) {
        const int d = (f & 1)*16 + lr;
        const bool isq = (f < 2);
        float bias = isq ? bq[d] : bk[d];
        unsigned short* hi = isq ? q_hi : k_hi;
        unsigned short* lo = isq ? q_lo : k_lo;
        #pragma unroll
        for (int r = 0; r < 4; r++) {
            int nn = n0 + lg*4 + r;
            float val = acc[f][r] + bias;
            unsigned short h = f2bf(val);
            unsigned short l2 = f2bf(val - bfval(h));
            size_t a = ((size_t)(b*NN + nn))*DD + d;
            hi[a] = h;
            lo[a] = l2;
        }
    }
}

// ---------------------------------------------------------------- proj_v
// Output layout BLOCKED: v16[b][ib=n/8][c][8] (f16), 16B per (ib,c) chunk.
__global__ __launch_bounds__(512) void proj_v(
    const float* __restrict__ x,
    const float* __restrict__ wv, const float* __restrict__ bv,
    _Float16* __restrict__ v16)
{
    const int t = threadIdx.x;
    const int w = t >> 6;
    const int cg = w >> 2;
    const int ng = w & 3;
    const int l = t & 63;
    const int lr = l & 15, lg = l >> 4;
    const int ob = blockIdx.x;
    const int nb = blockIdx.y;
    const int b  = blockIdx.z;
    const int n0 = nb*64 + ng*16;
    const int n  = n0 + lr;
    const int cbase0 = ob*128 + cg*64;

    const float* xb = x + (size_t)b*CCH*NN;

    f32x4 acc[4] = {};

    for (int kc = 0; kc < 8; kc++) {
        const int kbase = kc*32 + lg*8;
        float xv[8];
        #pragma unroll
        for (int e = 0; e < 8; e++)
            xv[e] = xb[(size_t)(kbase + e)*NN + n];
        bf16x8 xh, xl;
        #pragma unroll
        for (int e = 0; e < 8; e++) {
            unsigned short h = f2bf(xv[e]);
            xh[e] = (short)h;
            xl[e] = (short)f2bf(xv[e] - bfval(h));
        }
        #pragma unroll
        for (int f = 0; f < 4; f++) {
            const float* wrow = wv + (size_t)(cbase0 + f*16 + lr)*CCH;
            float4 a4 = *(const float4*)(wrow + kbase);
            float4 b4 = *(const float4*)(wrow + kbase + 4);
            float wv8[8] = {a4.x,a4.y,a4.z,a4.w,b4.x,b4.y,b4.z,b4.w};
            bf16x8 wh, wl;
            #pragma unroll
            for (int e = 0; e < 8; e++) {
                unsigned short h = f2bf(wv8[e]);
                wh[e] = (short)h;
                wl[e] = (short)f2bf(wv8[e] - bfval(h));
            }
            acc[f] = MFB(wl, xh, acc[f]);
            acc[f] = MFB(wh, xl, acc[f]);
            acc[f] = MFB(wh, xh, acc[f]);
        }
    }

    const size_t bslice = (size_t)b*(NN/8);
    #pragma unroll
    for (int f = 0; f < 4; f++) {
        #pragma unroll
        for (int r = 0; r < 4; r++) {
            int c = cbase0 + f*16 + lg*4 + r;
            float val = acc[f][r] + bv[c];
            v16[(((bslice + (n >> 3))*CCH + c) << 3) + (n & 7)] = (_Float16)val;
        }
    }
}

// ---------------------------------------------------------------- stats
// No max-tracking (energies bounded; 2^65 and sums << f32 max).
// Z = sum_j 2^(e*L2E) over a j-half; native v_exp_f32; K pointer-walk.
__global__ __launch_bounds__(512) void stats_kernel(
    const unsigned short* __restrict__ qh, const unsigned short* __restrict__ ql,
    const unsigned short* __restrict__ kh, const unsigned short* __restrict__ kl,
    float* __restrict__ Zp)
{
    __shared__ float zW[8][64];
    const int t = threadIdx.x;
    const int w = t >> 6;
    const int l = t & 63;
    const int lr = l & 15, lg = l >> 4;
    const int it = blockIdx.x;   // 0..63 : i-tile
    const int jc = blockIdx.y;   // 0..1  : j-half (2048 j each)
    const int b  = blockIdx.z;
    const int ibase = it*64;
    const f32x4 zero = {0.f,0.f,0.f,0.f};

    bf16x8 qfh[4], qfl[4];
    #pragma unroll
    for (int f = 0; f < 4; f++) {
        size_t a = ((size_t)(b*NN + ibase + f*16 + lr))*DD + lg*8;
        qfh[f] = *(const bf16x8*)(qh + a);
        qfl[f] = *(const bf16x8*)(ql + a);
    }
    float Z[4] = {0.f, 0.f, 0.f, 0.f};

    const size_t k0 = ((size_t)(b*NN + jc*2048 + w*16 + lr))*DD + lg*8;
    const unsigned short* kp  = kh + k0;
    const unsigned short* klp = kl + k0;

    for (int jt = 0; jt < 16; ++jt) {
        bf16x8 kfh2 = *(const bf16x8*)kp;
        bf16x8 kfl2 = *(const bf16x8*)klp;
        #pragma unroll
        for (int f = 0; f < 4; f++) {
            f32x4 e = MFB(kfl2, qfh[f], zero);
            e = MFB(kfh2, qfl[f], e);
            e = MFB(kfh2, qfh[f], e);
            Z[f] += vexp2(e[0]*L2E) + vexp2(e[1]*L2E)
                  + vexp2(e[2]*L2E) + vexp2(e[3]*L2E);
        }
        kp  += 128*DD;
        klp += 128*DD;
    }
    #pragma unroll
    for (int f = 0; f < 4; f++) {
        Z[f] += __shfl_xor(Z[f], 16, 64);
        Z[f] += __shfl_xor(Z[f], 32, 64);
        if (lg == 0) zW[w][f*16 + lr] = Z[f];
    }
    __syncthreads();
    if (t < 64) {
        float z = 0.f;
        #pragma unroll
        for (int w2 = 0; w2 < 8; ++w2) z += zW[w2][t];
        Zp[((size_t)jc*NB + b)*NN + ibase + t] = z;
    }
}

// ---------------------------------------------------------------- combine
__global__ __launch_bounds__(256) void combine_kernel(
    const float* __restrict__ Zp, float* __restrict__ Sx)
{
    const int idx = blockIdx.x*256 + threadIdx.x;   // b*NN + i, 16384 total
    Sx[idx] = log2f(Zp[idx] + Zp[(size_t)NB*NN + idx]);
}

// ---------------------------------------------------------------- attn
// R15: W (=V stream) taken OUT of LDS entirely -- the v16 blocked layout
// [ib][c][8] IS the PV B-fragment layout (lane lr=c, 16B = 8 consecutive i),
// so W loads go global(L2) -> VGPR directly, prefetched 1 iter ahead.
// j-tile 64->32, ct back to x2 (QK dup x4->x2), grid stays 1024 = 4/CU.
// Wave roles (zero intra-block duplication):
//   wave w: QK for i-frag ifr=w (6 MFB + 8 exp),
//           PV for c-frags {2w,2w+1} x both jj (8 MFH, 4 W loads).
// LDS = P double-buffer only (2x4KB); one barrier/iter.
__global__ __launch_bounds__(256, 4) void attn_kernel(
    const unsigned short* __restrict__ qh, const unsigned short* __restrict__ ql,
    const unsigned short* __restrict__ kh, const unsigned short* __restrict__ kl,
    const _Float16* __restrict__ v16,
    const float* __restrict__ Sx,
    const float* __restrict__ x, const float* __restrict__ gamma,
    float* __restrict__ out)
{
    __shared__ __align__(16) char Pb[2][4096];    // P [32j][64i] f16 swz, dbuf

    const int t = threadIdx.x;
    const int w = t >> 6;        // QK: ifr = w ; PV: c-frags {2w, 2w+1}
    const int l = t & 63;
    const int lr = l & 15, lg = l >> 4;

    // XCD slice: lin&7 = (b,ct) -> one slice per XCD (~1.6MB, L2-resident).
    const int lin = blockIdx.x;
    const int slice = lin & 7;
    const int b   = slice >> 1;
    const int ct  = slice & 1;
    const int jt  = lin >> 3;    // 0..127
    const int jbase = jt*32, cbase = ct*128;

    // K B-fragments for jj {0,1} (fixed all kernel)
    bf16x8 kfh[2], kfl[2];
    #pragma unroll
    for (int jj = 0; jj < 2; jj++) {
        size_t a = ((size_t)(b*NN + jbase + jj*16 + lr))*DD + lg*8;
        kfh[jj] = *(const bf16x8*)(kh + a);
        kfl[jj] = *(const bf16x8*)(kl + a);
    }

    const float* Sb = Sx + (size_t)b*NN;
    const _Float16* vb = v16 + (size_t)b*(NN/8)*CCH*8;

    // W walking pointer: lane (lr,lg) reads 16B chunk at ib = it*8+ic*4+lg,
    // c = cbase + (2w+cf)*16 + lr.  (ic -> +4*CCH*8 halves, cf -> +128)
    const _Float16* wpb = vb + (((size_t)lg*CCH + cbase + 2*w*16 + lr) << 3);

    // ---------------- prologue: prefetch W(0); compute P(0) ----------------
    f16x8 ws[2][2];
    #pragma unroll
    for (int ic = 0; ic < 2; ic++)
        #pragma unroll
        for (int cf = 0; cf < 2; cf++)
            ws[ic][cf] = *(const f16x8*)(wpb + ic*(4*CCH*8) + cf*128);
    wpb += 8*CCH*8;

    {
        size_t a = ((size_t)(b*NN + w*16 + lr))*DD + lg*8;
        bf16x8 qh2 = *(const bf16x8*)(qh + a);
        bf16x8 ql2 = *(const bf16x8*)(ql + a);
        float4 s4 = *(const float4*)(Sb + w*16 + lg*4);
        #pragma unroll
        for (int jj = 0; jj < 2; jj++) {
            f32x4 e = {};
            e = MFB(ql2, kfh[jj], e);
            e = MFB(qh2, kfl[jj], e);
            e = MFB(qh2, kfh[jj], e);
            double pk = pkpair(
                vexp2(fmaf(e[0], L2E, -s4.x)),
                vexp2(fmaf(e[1], L2E, -s4.y)),
                vexp2(fmaf(e[2], L2E, -s4.z)),
                vexp2(fmaf(e[3], L2E, -s4.w)));
            const int j = jj*16 + lr;
            const int slot = (w*2 + (lg>>1)) ^ (lr & 7);
            *(double*)(Pb[0] + j*128 + slot*16 + (lg&1)*8) = pk;
        }
    }
    __syncthreads();

    // walking pointers at it+1 = 1 positions
    const unsigned short* qhp =
        qh + ((size_t)(b*NN + 64 + w*16 + lr))*DD + lg*8;
    const unsigned short* qlp =
        ql + ((size_t)(b*NN + 64 + w*16 + lr))*DD + lg*8;
    const float* sp = Sb + 64 + w*16 + lg*4;

    char* Pcur = Pb[0]; char* Pnxt = Pb[1];

    f32x4 acc[2][2] = {};   // [jj][cf]

    for (int it = 0; it < 64; ++it) {
        const bool more = (it < 63);

        // ---- 1. issue global loads for it+1 (W, q, S; pointer walks) ----
        f16x8 wn[2][2];
        bf16x8 qh2, ql2;
        float4 s4;
        if (more) {
            #pragma unroll
            for (int ic = 0; ic < 2; ic++)
                #pragma unroll
                for (int cf = 0; cf < 2; cf++)
                    wn[ic][cf] = *(const f16x8*)(wpb + ic*(4*CCH*8) + cf*128);
            qh2 = *(const bf16x8*)qhp;
            ql2 = *(const bf16x8*)qlp;
            s4  = *(const float4*)sp;
        }

        // ---- 2. PV(it): pa from Pcur, W from prefetch regs ----
        f16x8 pa[2][2];
        #pragma unroll
        for (int jj = 0; jj < 2; jj++) {
            const int j = jj*16 + lr;
            #pragma unroll
            for (int ic = 0; ic < 2; ic++) {
                const int slot = (ic*4 + lg) ^ (lr & 7);
                pa[jj][ic] = *(const f16x8*)(Pcur + j*128 + slot*16);
            }
        }
        __builtin_amdgcn_s_setprio(1);
        #pragma unroll
        for (int ic = 0; ic < 2; ic++) {
            #pragma unroll
            for (int cf = 0; cf < 2; cf++) {
                acc[0][cf] = MFH(pa[0][ic], ws[ic][cf], acc[0][cf]);
                acc[1][cf] = MFH(pa[1][ic], ws[ic][cf], acc[1][cf]);
            }
        }
        __builtin_amdgcn_s_setprio(0);

        // ---- 3. QK(it+1) + exp/pack -> Pnxt; rotate W prefetch ----
        if (more) {
            #pragma unroll
            for (int jj = 0; jj < 2; jj++) {
                f32x4 e = {};
                e = MFB(ql2, kfh[jj], e);
                e = MFB(qh2, kfl[jj], e);
                e = MFB(qh2, kfh[jj], e);
                double pk = pkpair(
                    vexp2(fmaf(e[0], L2E, -s4.x)),
                    vexp2(fmaf(e[1], L2E, -s4.y)),
                    vexp2(fmaf(e[2], L2E, -s4.z)),
                    vexp2(fmaf(e[3], L2E, -s4.w)));
                const int j = jj*16 + lr;
                const int slot = (w*2 + (lg>>1)) ^ (lr & 7);
                *(double*)(Pnxt + j*128 + slot*16 + (lg&1)*8) = pk;
            }
            #pragma unroll
            for (int ic = 0; ic < 2; ic++)
                #pragma unroll
                for (int cf = 0; cf < 2; cf++)
                    ws[ic][cf] = wn[ic][cf];
        }
        __syncthreads();

        wpb += 8*CCH*8;     // next i-tile (8 ib-steps)
        qhp += 64*DD;
        qlp += 64*DD;
        sp  += 64;
        char* tp = Pcur; Pcur = Pnxt; Pnxt = tp;
    }

    // epilogue: direct float4 stores (j contiguous in NN dim)
    const float gam = gamma[0];
    #pragma unroll
    for (int jj = 0; jj < 2; jj++) {
        #pragma unroll
        for (int cf = 0; cf < 2; cf++) {
            const int c = cbase + (2*w+cf)*16 + lr;
            const int j = jbase + jj*16 + lg*4;
            size_t o = ((size_t)(b*CCH + c))*NN + j;
            float4 xv = *(const float4*)(x + o);
            float4 ov;
            ov.x = fmaf(gam, acc[jj][cf][0], xv.x);
            ov.y = fmaf(gam, acc[jj][cf][1], xv.y);
            ov.z = fmaf(gam, acc[jj][cf][2], xv.z);
            ov.w = fmaf(gam, acc[jj][cf][3], xv.w);
            *(float4*)(out + o) = ov;
        }
    }
}

// ---------------------------------------------------------------- launch
extern "C" void kernel_launch(void* const* d_in, const int* in_sizes, int n_in,
                              void* d_out, int out_size, void* d_ws, size_t ws_size,
                              hipStream_t stream)
{
    (void)in_sizes; (void)n_in; (void)out_size; (void)ws_size;
    const float* x     = (const float*)d_in[0];
    const float* wq    = (const float*)d_in[1];
    const float* bq    = (const float*)d_in[2];
    const float* wk    = (const float*)d_in[3];
    const float* bk    = (const float*)d_in[4];
    const float* wv    = (const float*)d_in[5];
    const float* bv    = (const float*)d_in[6];
    const float* gamma = (const float*)d_in[7];
    float* out = (float*)d_out;

    char* ws = (char*)d_ws;
    unsigned short* q_hi = (unsigned short*)(ws + 0x000000);  // 1MB
    unsigned short* q_lo = (unsigned short*)(ws + 0x100000);  // 1MB
    unsigned short* k_hi = (unsigned short*)(ws + 0x200000);  // 1MB
    unsigned short* k_lo = (unsigned short*)(ws + 0x300000);  // 1MB
    _Float16*       v16  = (_Float16*)      (ws + 0x400000);  // 8MB blocked
    float*          Zp   = (float*)         (ws + 0xC00000);  // 128KB partials
    float*          Sx   = (float*)         (ws + 0xC20000);  // 64KB (SL)

    proj_qk<<<dim3(64, 4),    256, 0, stream>>>(x, wq, bq, wk, bk,
                                                q_hi, q_lo, k_hi, k_lo);
    proj_v <<<dim3(2, 64, 4), 512, 0, stream>>>(x, wv, bv, v16);
    stats_kernel  <<<dim3(64, 2, 4), 512, 0, stream>>>(q_hi, q_lo, k_hi, k_lo, Zp);
    combine_kernel<<<dim3(64),       256, 0, stream>>>(Zp, Sx);
    attn_kernel   <<<dim3(1024),     256, 0, stream>>>(
        q_hi, q_lo, k_hi, k_lo, v16, Sx, x, gamma, out);
}

// Round 3
// 164.944 us; speedup vs baseline: 1.0760x; 1.0487x over previous
//
#include <hip/hip_runtime.h>

#define NB 4
#define CCH 256
#define NN 4096
#define DD 32

typedef __attribute__((ext_vector_type(8))) short bf16x8;
typedef __attribute__((ext_vector_type(8))) _Float16 f16x8;
typedef __attribute__((ext_vector_type(2))) __fp16 fp16x2;
typedef __attribute__((ext_vector_type(4))) float f32x4;

#define MFB(a,b,c) __builtin_amdgcn_mfma_f32_16x16x32_bf16(a,b,c,0,0,0)
#define MFH(a,b,c) __builtin_amdgcn_mfma_f32_16x16x32_f16(a,b,c,0,0,0)
#define L2E 1.44269504f

__device__ inline unsigned short f2bf(float f){
    union { float f; unsigned u; } v; v.f = f;
    unsigned r = v.u + 0x7fffu + ((v.u >> 16) & 1u);
    return (unsigned short)(r >> 16);
}
__device__ inline float bfval(unsigned short h){
    union { unsigned u; float f; } v; v.u = ((unsigned)h) << 16; return v.f;
}
// native transcendental: D = 2^S0 (exactly what SL-folded softmax needs)
__device__ inline float vexp2(float x){
    float r; asm("v_exp_f32 %0, %1" : "=v"(r) : "v"(x)); return r;
}
__device__ inline double pkpair(float p0, float p1, float p2, float p3){
    union { fp16x2 h2[2]; double d; } u;
    u.h2[0] = __builtin_amdgcn_cvt_pkrtz(p0, p1);
    u.h2[1] = __builtin_amdgcn_cvt_pkrtz(p2, p3);
    return u.d;
}

// ---------------------------------------------------------------- proj_qk
__global__ __launch_bounds__(256) void proj_qk(
    const float* __restrict__ x,
    const float* __restrict__ wq, const float* __restrict__ bq,
    const float* __restrict__ wk, const float* __restrict__ bk,
    unsigned short* __restrict__ q_hi, unsigned short* __restrict__ q_lo,
    unsigned short* __restrict__ k_hi, unsigned short* __restrict__ k_lo)
{
    const int t = threadIdx.x;
    const int w = t >> 6;
    const int l = t & 63;
    const int lr = l & 15, lg = l >> 4;
    const int nb = blockIdx.x;
    const int b  = blockIdx.y;
    const int n0 = nb*64 + w*16;
    const int n  = n0 + lr;

    const float* xb = x + (size_t)b*CCH*NN;

    f32x4 acc[4] = {};

    for (int kc = 0; kc < 8; kc++) {
        const int cbase = kc*32 + lg*8;
        float xv[8];
        #pragma unroll
        for (int e = 0; e < 8; e++)
            xv[e] = xb[(size_t)(cbase + e)*NN + n];
        bf16x8 xh, xl;
        #pragma unroll
        for (int e = 0; e < 8; e++) {
            unsigned short h = f2bf(xv[e]);
            xh[e] = (short)h;
            xl[e] = (short)f2bf(xv[e] - bfval(h));
        }
        #pragma unroll
        for (int f = 0; f < 4; f++) {
            const float* wrow = (f < 2) ? (wq + (size_t)(f*16 + lr)*CCH)
                                        : (wk + (size_t)((f-2)*16 + lr)*CCH);
            float4 a4 = *(const float4*)(wrow + cbase);
            float4 b4 = *(const float4*)(wrow + cbase + 4);
            float wv8[8] = {a4.x,a4.y,a4.z,a4.w,b4.x,b4.y,b4.z,b4.w};
            bf16x8 wh, wl;
            #pragma unroll
            for (int e = 0; e < 8; e++) {
                unsigned short h = f2bf(wv8[e]);
                wh[e] = (short)h;
                wl[e] = (short)f2bf(wv8[e] - bfval(h));
            }
            acc[f] = MFB(xh, wl, acc[f]);
            acc[f] = MFB(xl, wh, acc[f]);
            acc[f] = MFB(xh, wh, acc[f]);
        }
    }

    #pragma unroll
    for (int f = 0; f < 4; f++) {
        const int d = (f & 1)*16 + lr;
        const bool isq = (f < 2);
        float bias = isq ? bq[d] : bk[d];
        unsigned short* hi = isq ? q_hi : k_hi;
        unsigned short* lo = isq ? q_lo : k_lo;
        #pragma unroll
        for (int r = 0; r < 4; r++) {
            int nn = n0 + lg*4 + r;
            float val = acc[f][r] + bias;
            unsigned short h = f2bf(val);
            unsigned short l2 = f2bf(val - bfval(h));
            size_t a = ((size_t)(b*NN + nn))*DD + d;
            hi[a] = h;
            lo[a] = l2;
        }
    }
}

// ---------------------------------------------------------------- proj_v
// Output layout BLOCKED: v16[b][ib=n/8][c][8] (f16), 16B per (ib,c) chunk.
__global__ __launch_bounds__(512) void proj_v(
    const float* __restrict__ x,
    const float* __restrict__ wv, const float* __restrict__ bv,
    _Float16* __restrict__ v16)
{
    const int t = threadIdx.x;
    const int w = t >> 6;
    const int cg = w >> 2;
    const int ng = w & 3;
    const int l = t & 63;
    const int lr = l & 15, lg = l >> 4;
    const int ob = blockIdx.x;
    const int nb = blockIdx.y;
    const int b  = blockIdx.z;
    const int n0 = nb*64 + ng*16;
    const int n  = n0 + lr;
    const int cbase0 = ob*128 + cg*64;

    const float* xb = x + (size_t)b*CCH*NN;

    f32x4 acc[4] = {};

    for (int kc = 0; kc < 8; kc++) {
        const int kbase = kc*32 + lg*8;
        float xv[8];
        #pragma unroll
        for (int e = 0; e < 8; e++)
            xv[e] = xb[(size_t)(kbase + e)*NN + n];
        bf16x8 xh, xl;
        #pragma unroll
        for (int e = 0; e < 8; e++) {
            unsigned short h = f2bf(xv[e]);
            xh[e] = (short)h;
            xl[e] = (short)f2bf(xv[e] - bfval(h));
        }
        #pragma unroll
        for (int f = 0; f < 4; f++) {
            const float* wrow = wv + (size_t)(cbase0 + f*16 + lr)*CCH;
            float4 a4 = *(const float4*)(wrow + kbase);
            float4 b4 = *(const float4*)(wrow + kbase + 4);
            float wv8[8] = {a4.x,a4.y,a4.z,a4.w,b4.x,b4.y,b4.z,b4.w};
            bf16x8 wh, wl;
            #pragma unroll
            for (int e = 0; e < 8; e++) {
                unsigned short h = f2bf(wv8[e]);
                wh[e] = (short)h;
                wl[e] = (short)f2bf(wv8[e] - bfval(h));
            }
            acc[f] = MFB(wl, xh, acc[f]);
            acc[f] = MFB(wh, xl, acc[f]);
            acc[f] = MFB(wh, xh, acc[f]);
        }
    }

    const size_t bslice = (size_t)b*(NN/8);
    #pragma unroll
    for (int f = 0; f < 4; f++) {
        #pragma unroll
        for (int r = 0; r < 4; r++) {
            int c = cbase0 + f*16 + lg*4 + r;
            float val = acc[f][r] + bv[c];
            v16[(((bslice + (n >> 3))*CCH + c) << 3) + (n & 7)] = (_Float16)val;
        }
    }
}

// ---------------------------------------------------------------- stats
// No max-tracking (energies bounded; 2^65 and sums << f32 max).
// Z = sum_j 2^(e*L2E) over a j-half; native v_exp_f32; K pointer-walk.
__global__ __launch_bounds__(512) void stats_kernel(
    const unsigned short* __restrict__ qh, const unsigned short* __restrict__ ql,
    const unsigned short* __restrict__ kh, const unsigned short* __restrict__ kl,
    float* __restrict__ Zp)
{
    __shared__ float zW[8][64];
    const int t = threadIdx.x;
    const int w = t >> 6;
    const int l = t & 63;
    const int lr = l & 15, lg = l >> 4;
    const int it = blockIdx.x;   // 0..63 : i-tile
    const int jc = blockIdx.y;   // 0..1  : j-half (2048 j each)
    const int b  = blockIdx.z;
    const int ibase = it*64;
    const f32x4 zero = {0.f,0.f,0.f,0.f};

    bf16x8 qfh[4], qfl[4];
    #pragma unroll
    for (int f = 0; f < 4; f++) {
        size_t a = ((size_t)(b*NN + ibase + f*16 + lr))*DD + lg*8;
        qfh[f] = *(const bf16x8*)(qh + a);
        qfl[f] = *(const bf16x8*)(ql + a);
    }
    float Z[4] = {0.f, 0.f, 0.f, 0.f};

    const size_t k0 = ((size_t)(b*NN + jc*2048 + w*16 + lr))*DD + lg*8;
    const unsigned short* kp  = kh + k0;
    const unsigned short* klp = kl + k0;

    for (int jt = 0; jt < 16; ++jt) {
        bf16x8 kfh2 = *(const bf16x8*)kp;
        bf16x8 kfl2 = *(const bf16x8*)klp;
        #pragma unroll
        for (int f = 0; f < 4; f++) {
            f32x4 e = MFB(kfl2, qfh[f], zero);
            e = MFB(kfh2, qfl[f], e);
            e = MFB(kfh2, qfh[f], e);
            Z[f] += vexp2(e[0]*L2E) + vexp2(e[1]*L2E)
                  + vexp2(e[2]*L2E) + vexp2(e[3]*L2E);
        }
        kp  += 128*DD;
        klp += 128*DD;
    }
    #pragma unroll
    for (int f = 0; f < 4; f++) {
        Z[f] += __shfl_xor(Z[f], 16, 64);
        Z[f] += __shfl_xor(Z[f], 32, 64);
        if (lg == 0) zW[w][f*16 + lr] = Z[f];
    }
    __syncthreads();
    if (t < 64) {
        float z = 0.f;
        #pragma unroll
        for (int w2 = 0; w2 < 8; ++w2) z += zW[w2][t];
        Zp[((size_t)jc*NB + b)*NN + ibase + t] = z;
    }
}

// ---------------------------------------------------------------- combine
__global__ __launch_bounds__(256) void combine_kernel(
    const float* __restrict__ Zp, float* __restrict__ Sx)
{
    const int idx = blockIdx.x*256 + threadIdx.x;   // b*NN + i, 16384 total
    Sx[idx] = log2f(Zp[idx] + Zp[(size_t)NB*NN + idx]);
}

// ---------------------------------------------------------------- attn
// R16: L2-traffic reduction. R15 evidence: doubling blocks/CU (R13 2/CU ->
// R15 4/CU) left per-iter time ~flat => shared-resource bound, and the
// arithmetic points at L2: W re-reads = 32GB/JT (1.07GB at JT=32) + q
// re-reads (0.5GB) = 16 TB/s ~ 47% of L2 ceiling at 105us.
// Fix: JT 32->64 with 8-wave (512-thr) blocks; per-WAVE-iter instruction
// mix is IDENTICAL to R15 (6 MFB, 8 MFH, 8 exp, 4 W loads, 2 q, 4 ds_read,
// 2 ds_write); wave residency identical (4 waves/SIMD). W traffic halves
// to 0.5GB, q to 0.26GB. W-prefetch ping-pong via 2x unroll (no reg copies).
// Wave roles: wj=w>>2 -> j-frag pair {2wj,2wj+1} (K frags fixed in regs);
//             wi=w&3  -> QK i-frag wi, PV c-frag pair {2wi,2wi+1}.
__global__ __launch_bounds__(512, 4) void attn_kernel(
    const unsigned short* __restrict__ qh, const unsigned short* __restrict__ ql,
    const unsigned short* __restrict__ kh, const unsigned short* __restrict__ kl,
    const _Float16* __restrict__ v16,
    const float* __restrict__ Sx,
    const float* __restrict__ x, const float* __restrict__ gamma,
    float* __restrict__ out)
{
    __shared__ __align__(16) char Pb[2][8192];    // P [64j][64i] f16 swz, dbuf

    const int t = threadIdx.x;
    const int w = t >> 6;
    const int wj = w >> 2;       // 0..1 : j-frag pair
    const int wi = w & 3;        // 0..3 : QK i-frag / PV c-frag pair
    const int l = t & 63;
    const int lr = l & 15, lg = l >> 4;

    // XCD slice: lin&7 = (b,ct) -> one slice per XCD (~2MB, L2-resident).
    const int lin = blockIdx.x;
    const int slice = lin & 7;
    const int b   = slice >> 1;
    const int ct  = slice & 1;
    const int jt  = lin >> 3;    // 0..63
    const int jbase = jt*64, cbase = ct*128;

    // K B-fragments for jfr {2wj, 2wj+1} (fixed all kernel)
    bf16x8 kfh[2], kfl[2];
    #pragma unroll
    for (int jj = 0; jj < 2; jj++) {
        size_t a = ((size_t)(b*NN + jbase + (2*wj+jj)*16 + lr))*DD + lg*8;
        kfh[jj] = *(const bf16x8*)(kh + a);
        kfl[jj] = *(const bf16x8*)(kl + a);
    }

    const float* Sb = Sx + (size_t)b*NN;
    const _Float16* vb = v16 + (size_t)b*(NN/8)*CCH*8;

    // W walking pointer: lane (lr,lg) reads 16B chunk at ib = it*8+ic*4+lg,
    // c = cbase + (2wi+cf)*16 + lr.  (ic -> +4*CCH*8, cf -> +128 elems)
    const _Float16* wpb = vb + (((size_t)lg*CCH + cbase + 2*wi*16 + lr) << 3);

    // W prefetch ping-pong buffers (no copies: 2x-unrolled loop swaps roles)
    f16x8 wpre[2][2][2];   // [buf][ic][cf]

    // ---------------- prologue: prefetch W(0); compute P(0) ----------------
    #pragma unroll
    for (int ic = 0; ic < 2; ic++)
        #pragma unroll
        for (int cf = 0; cf < 2; cf++)
            wpre[0][ic][cf] = *(const f16x8*)(wpb + ic*(4*CCH*8) + cf*128);
    wpb += 8*CCH*8;

    {
        size_t a = ((size_t)(b*NN + wi*16 + lr))*DD + lg*8;
        bf16x8 qh2 = *(const bf16x8*)(qh + a);
        bf16x8 ql2 = *(const bf16x8*)(ql + a);
        float4 s4 = *(const float4*)(Sb + wi*16 + lg*4);
        #pragma unroll
        for (int jj = 0; jj < 2; jj++) {
            f32x4 e = {};
            e = MFB(ql2, kfh[jj], e);
            e = MFB(qh2, kfl[jj], e);
            e = MFB(qh2, kfh[jj], e);
            double pk = pkpair(
                vexp2(fmaf(e[0], L2E, -s4.x)),
                vexp2(fmaf(e[1], L2E, -s4.y)),
                vexp2(fmaf(e[2], L2E, -s4.z)),
                vexp2(fmaf(e[3], L2E, -s4.w)));
            const int j = (2*wj+jj)*16 + lr;
            const int slot = (wi*2 + (lg>>1)) ^ (lr & 7);
            *(double*)(Pb[0] + j*128 + slot*16 + (lg&1)*8) = pk;
        }
    }
    __syncthreads();

    // walking pointers at it+1 = 1 positions
    const unsigned short* qhp =
        qh + ((size_t)(b*NN + 64 + wi*16 + lr))*DD + lg*8;
    const unsigned short* qlp =
        ql + ((size_t)(b*NN + 64 + wi*16 + lr))*DD + lg*8;
    const float* sp = Sb + 64 + wi*16 + lg*4;

    f32x4 acc[2][2] = {};   // [jj][cf]

    auto body = [&](f16x8 (&ws)[2][2], f16x8 (&wn)[2][2],
                    char* Pcur, char* Pnxt, bool more) {
        // ---- 1. issue global loads for it+1 (W, q, S; pointer walks) ----
        bf16x8 qh2, ql2;
        float4 s4;
        if (more) {
            #pragma unroll
            for (int ic = 0; ic < 2; ic++)
                #pragma unroll
                for (int cf = 0; cf < 2; cf++)
                    wn[ic][cf] = *(const f16x8*)(wpb + ic*(4*CCH*8) + cf*128);
            qh2 = *(const bf16x8*)qhp;
            ql2 = *(const bf16x8*)qlp;
            s4  = *(const float4*)sp;
        }

        // ---- 2. PV(it): pa from Pcur, W from prefetch regs ----
        f16x8 pa[2][2];
        #pragma unroll
        for (int jj = 0; jj < 2; jj++) {
            const int j = (2*wj+jj)*16 + lr;
            #pragma unroll
            for (int ic = 0; ic < 2; ic++) {
                const int slot = (ic*4 + lg) ^ (lr & 7);
                pa[jj][ic] = *(const f16x8*)(Pcur + j*128 + slot*16);
            }
        }
        __builtin_amdgcn_s_setprio(1);
        #pragma unroll
        for (int ic = 0; ic < 2; ic++) {
            #pragma unroll
            for (int cf = 0; cf < 2; cf++) {
                acc[0][cf] = MFH(pa[0][ic], ws[ic][cf], acc[0][cf]);
                acc[1][cf] = MFH(pa[1][ic], ws[ic][cf], acc[1][cf]);
            }
        }
        __builtin_amdgcn_s_setprio(0);

        // ---- 3. QK(it+1) + exp/pack -> Pnxt ----
        if (more) {
            #pragma unroll
            for (int jj = 0; jj < 2; jj++) {
                f32x4 e = {};
                e = MFB(ql2, kfh[jj], e);
                e = MFB(qh2, kfl[jj], e);
                e = MFB(qh2, kfh[jj], e);
                double pk = pkpair(
                    vexp2(fmaf(e[0], L2E, -s4.x)),
                    vexp2(fmaf(e[1], L2E, -s4.y)),
                    vexp2(fmaf(e[2], L2E, -s4.z)),
                    vexp2(fmaf(e[3], L2E, -s4.w)));
                const int j = (2*wj+jj)*16 + lr;
                const int slot = (wi*2 + (lg>>1)) ^ (lr & 7);
                *(double*)(Pnxt + j*128 + slot*16 + (lg&1)*8) = pk;
            }
        }
        __syncthreads();

        wpb += 8*CCH*8;     // next i-tile (8 ib-steps)
        qhp += 64*DD;
        qlp += 64*DD;
        sp  += 64;
    };

    for (int it = 0; it < 64; it += 2) {
        body(wpre[0], wpre[1], Pb[0], Pb[1], it < 63);
        body(wpre[1], wpre[0], Pb[1], Pb[0], it < 62);
    }

    // epilogue: direct float4 stores (j contiguous in NN dim)
    const float gam = gamma[0];
    #pragma unroll
    for (int jj = 0; jj < 2; jj++) {
        #pragma unroll
        for (int cf = 0; cf < 2; cf++) {
            const int c = cbase + (2*wi+cf)*16 + lr;
            const int j = jbase + (2*wj+jj)*16 + lg*4;
            size_t o = ((size_t)(b*CCH + c))*NN + j;
            float4 xv = *(const float4*)(x + o);
            float4 ov;
            ov.x = fmaf(gam, acc[jj][cf][0], xv.x);
            ov.y = fmaf(gam, acc[jj][cf][1], xv.y);
            ov.z = fmaf(gam, acc[jj][cf][2], xv.z);
            ov.w = fmaf(gam, acc[jj][cf][3], xv.w);
            *(float4*)(out + o) = ov;
        }
    }
}

// ---------------------------------------------------------------- launch
extern "C" void kernel_launch(void* const* d_in, const int* in_sizes, int n_in,
                              void* d_out, int out_size, void* d_ws, size_t ws_size,
                              hipStream_t stream)
{
    (void)in_sizes; (void)n_in; (void)out_size; (void)ws_size;
    const float* x     = (const float*)d_in[0];
    const float* wq    = (const float*)d_in[1];
    const float* bq    = (const float*)d_in[2];
    const float* wk    = (const float*)d_in[3];
    const float* bk    = (const float*)d_in[4];
    const float* wv    = (const float*)d_in[5];
    const float* bv    = (const float*)d_in[6];
    const float* gamma = (const float*)d_in[7];
    float* out = (float*)d_out;

    char* ws = (char*)d_ws;
    unsigned short* q_hi = (unsigned short*)(ws + 0x000000);  // 1MB
    unsigned short* q_lo = (unsigned short*)(ws + 0x100000);  // 1MB
    unsigned short* k_hi = (unsigned short*)(ws + 0x200000);  // 1MB
    unsigned short* k_lo = (unsigned short*)(ws + 0x300000);  // 1MB
    _Float16*       v16  = (_Float16*)      (ws + 0x400000);  // 8MB blocked
    float*          Zp   = (float*)         (ws + 0xC00000);  // 128KB partials
    float*          Sx   = (float*)         (ws + 0xC20000);  // 64KB (SL)

    proj_qk<<<dim3(64, 4),    256, 0, stream>>>(x, wq, bq, wk, bk,
                                                q_hi, q_lo, k_hi, k_lo);
    proj_v <<<dim3(2, 64, 4), 512, 0, stream>>>(x, wv, bv, v16);
    stats_kernel  <<<dim3(64, 2, 4), 512, 0, stream>>>(q_hi, q_lo, k_hi, k_lo, Zp);
    combine_kernel<<<dim3(64),       256, 0, stream>>>(Zp, Sx);
    attn_kernel   <<<dim3(512),      512, 0, stream>>>(
        q_hi, q_lo, k_hi, k_lo, v16, Sx, x, gamma, out);
}